// Round 8
// baseline (152.501 us; speedup 1.0000x reference)
//
#include <hip/hip_runtime.h>

// input_tensor: [8,128,128,128,1] fp32 ; random_u: [8,8,3] fp32 ; SCALE=0.2
#define NB   8
#define NS   128
#define VOX  (NS*NS*NS)

// R8: NO LDS STAGING. Counters across R0-R7 show: all pipes ~10 us yet wall
// time pinned at 40-42 us; occupancy 2.8 blocks/CU (35%) with 6 resident
// possible; FETCH 27 MB << 67 MB input (input is L2/L3-resident). The block-
// serial chain {stage -> barrier+vmcnt(0) drain -> LDS roundtrip} is the
// exposed-latency floor, and it re-buffers data the caches already hold
// (Common-mistake #7). R8 reads the 8 taps per voxel directly from global:
// lanes are dense along w and t22 in [0.8,1], so lane wl reads ~base+wl —
// near-coalesced; the 27 KB tile window flows through L1/L2 on demand.
// Deleted: barrier, DMA drain, zero-fill, staging addressing, all DS traffic
// (and its 3.27M conflict cycles). Boundary semantics: per-axis zero-weight
// masks + clamped (always in-bounds) addresses, on the block-uniform
// non-interior path only — exact reference semantics (R0-proven).
// Tile 32w x 8h x 8d, 256 threads, 8 voxels/thread along d; fast-path index
// math in fp32 is exact: i0*16384 + i1*128 + i2 <= 2,097,151 < 2^24.

typedef float vf2 __attribute__((ext_vector_type(2)));

__global__ __launch_bounds__(256) void warp_resample_kernel(
        const float* __restrict__ img, const float* __restrict__ u,
        float* __restrict__ out) {
    const int tid = threadIdx.x;
    // XCD pinning (R3/R7-verified: FETCH 70->27 MB): b = bi&7 -> one batch
    // per XCD-private L2; concurrent blocks on an XCD share ~2.5 MB of planes.
    const int bi   = blockIdx.x;
    const int b    =  bi & 7;
    const int idx  =  bi >> 3;
    const int wblk =  idx & 3;          // 4 w-tiles of 32
    const int hblk = (idx >> 2) & 15;   // 16 h-tiles of 8
    const int dblk =  idx >> 6;         // 16 d-tiles of 8

    // ---- transform: all lanes uniform (Walsh butterfly; 1/8 folded in) ----
    const float* ub = u + b * 24;
    float T[3][4];
#pragma unroll
    for (int i = 0; i < 3; ++i) {
        float v[8];
#pragma unroll
        for (int n = 0; n < 8; ++n) {
            const float sg = (n & (4 >> i)) ? 1.f : -1.f;
            v[n] = fmaf(sg * 0.025f, ub[n * 3 + i], sg * 0.1f);  // sg*(0.8+0.2u)/8
        }
        const float a0 = v[0] + v[1], a1 = v[2] + v[3];
        const float a2 = v[4] + v[5], a3 = v[6] + v[7];
        const float d0 = v[1] - v[0], d1 = v[3] - v[2];
        const float d2 = v[5] - v[4], d3 = v[7] - v[6];
        const float A01 = a0 + a1, A23 = a2 + a3;
        T[i][0] = A23 - A01;
        T[i][1] = (a1 - a0) + (a3 - a2);
        T[i][2] = (d0 + d1) + (d2 + d3);
        T[i][3] = A01 + A23;
    }
    const float t00 = T[0][0], t01 = T[0][1], t02 = T[0][2], t03 = T[0][3];
    const float t10 = T[1][0], t11 = T[1][1], t12 = T[1][2], t13 = T[1][3];
    const float t20 = T[2][0], t21 = T[2][1], t22 = T[2][2], t23 = T[2][3];

    const int d0i = dblk << 3, h0i = hblk << 3, w0i = wblk << 5;
    const float inv = 2.0f / 127.0f;
    const float x0 = -1.f + d0i * inv, y0 = -1.f + h0i * inv, z0 = -1.f + w0i * inv;
    // pixel coords at tile origin; per-index pixel delta == t (inv*63.5 == 1)
    const float P0 = (t00 * x0 + t01 * y0 + t02 * z0 + t03 + 1.f) * 63.5f;
    const float P1 = (t10 * x0 + t11 * y0 + t12 * z0 + t13 + 1.f) * 63.5f;
    const float P2 = (t20 * x0 + t21 * y0 + t22 * z0 + t23 + 1.f) * 63.5f;

    // tile bounds via corner extremes (kd<=7, kh<=7, kw<=31)
    const float mn0 = P0 + fminf(0.f,7.f*t00)+fminf(0.f,7.f*t01)+fminf(0.f,31.f*t02);
    const float mx0 = P0 + fmaxf(0.f,7.f*t00)+fmaxf(0.f,7.f*t01)+fmaxf(0.f,31.f*t02);
    const float mn1 = P1 + fminf(0.f,7.f*t10)+fminf(0.f,7.f*t11)+fminf(0.f,31.f*t12);
    const float mx1 = P1 + fmaxf(0.f,7.f*t10)+fmaxf(0.f,7.f*t11)+fmaxf(0.f,31.f*t12);
    const float mn2 = P2 + fminf(0.f,7.f*t20)+fminf(0.f,7.f*t21)+fminf(0.f,31.f*t22);
    const float mx2 = P2 + fmaxf(0.f,7.f*t20)+fmaxf(0.f,7.f*t21)+fmaxf(0.f,31.f*t22);

    const int i0mn = (int)floorf(mn0), i0mx = (int)floorf(mx0);
    const int i1mn = (int)floorf(mn1), i1mx = (int)floorf(mx1);
    const int i2mn = (int)floorf(mn2), i2mx = (int)floorf(mx2);

    // block-uniform: every tap (i, i+1) of every voxel inside the image?
    const int interior = __builtin_amdgcn_readfirstlane(
        (i0mn >= 0 && i0mx <= NS - 2 &&
         i1mn >= 0 && i1mx <= NS - 2 &&
         i2mn >= 0 && i2mx <= NS - 2) ? 1 : 0);

    const float* gb = img + (size_t)b * VOX;
    const int wl = tid & 31, hh = tid >> 5;
    float q0 = P0 + hh * t01 + wl * t02;
    float q1 = P1 + hh * t11 + wl * t12;
    float q2 = P2 + hh * t21 + wl * t22;

    float res[8];

    if (interior) {
        // all q >= 0; all 8 taps provably in-bounds -> unchecked loads
#pragma unroll
        for (int k = 0; k < 8; ++k) {
            const float f0 = floorf(q0), f1 = floorf(q1), f2 = floorf(q2);
            const float r0 = q0 - f0,    r1 = q1 - f1,    r2 = q2 - f2;
            // exact fp32 voxel index: i0*16384 + i1*128 + i2 (< 2^24)
            const int vx = (int)fmaf(f0, 16384.f, fmaf(f1, 128.f, f2));
            const float* p0 = gb + vx;            // (d,   h)
            const float* p1 = gb + vx + NS * NS;  // (d+1, h)  +64KB plane

            const float a00 = p0[0],       b00 = p0[1];        // offsets 0,4
            const float a01 = p0[NS],      b01 = p0[NS + 1];   // offsets 512,516
            const float a10 = p1[0],       b10 = p1[1];
            const float a11 = p1[NS],      b11 = p1[NS + 1];

            const float e0 = fmaf(r2, b00 - a00, a00);
            const float e1 = fmaf(r2, b01 - a01, a01);
            const float e2 = fmaf(r2, b10 - a10, a10);
            const float e3 = fmaf(r2, b11 - a11, a11);
            const float c0 = fmaf(r1, e1 - e0, e0);
            const float c1 = fmaf(r1, e3 - e2, e2);
            res[k] = fmaf(r0, c1 - c0, c0);

            q0 += t00; q1 += t10; q2 += t20;
        }
    } else {
        // boundary: per-axis zero-weight masks (reference semantics), clamped
        // (always in-bounds) addresses; value under a zero weight is harmless
#pragma unroll
        for (int k = 0; k < 8; ++k) {
            const float f0 = floorf(q0), f1 = floorf(q1), f2 = floorf(q2);
            const float r0 = q0 - f0,    r1 = q1 - f1,    r2 = q2 - f2;
            const int   i0 = (int)f0,    i1 = (int)f1,    i2 = (int)f2;

            const float wd0 = ((unsigned)i0       < NS) ? 1.f - r0 : 0.f;
            const float wd1 = ((unsigned)(i0 + 1) < NS) ? r0       : 0.f;
            const float wh0 = ((unsigned)i1       < NS) ? 1.f - r1 : 0.f;
            const float wh1 = ((unsigned)(i1 + 1) < NS) ? r1       : 0.f;
            const float ww0 = ((unsigned)i2       < NS) ? 1.f - r2 : 0.f;
            const float ww1 = ((unsigned)(i2 + 1) < NS) ? r2       : 0.f;

            const int da = min(max(i0,     0), NS - 1);
            const int db = min(max(i0 + 1, 0), NS - 1);
            const int ha = min(max(i1,     0), NS - 1);
            const int hb = min(max(i1 + 1, 0), NS - 1);
            const int wa = min(max(i2,     0), NS - 1);
            const int wb = min(max(i2 + 1, 0), NS - 1);

            const int ra00 = (da * NS + ha) * NS;
            const int ra01 = (da * NS + hb) * NS;
            const int ra10 = (db * NS + ha) * NS;
            const int ra11 = (db * NS + hb) * NS;

            const float e00 = gb[ra00 + wa] * ww0 + gb[ra00 + wb] * ww1;
            const float e01 = gb[ra01 + wa] * ww0 + gb[ra01 + wb] * ww1;
            const float e10 = gb[ra10 + wa] * ww0 + gb[ra10 + wb] * ww1;
            const float e11 = gb[ra11 + wa] * ww0 + gb[ra11 + wb] * ww1;

            res[k] = wd0 * fmaf(e00, wh0, e01 * wh1)
                   + wd1 * fmaf(e10, wh0, e11 * wh1);

            q0 += t00; q1 += t10; q2 += t20;
        }
    }

    // stores: wave = 2 h-rows x 32 consecutive w -> coalesced 128B segments
    size_t ob = (((size_t)(b * NS + d0i) * NS + (h0i + hh)) * NS) + w0i + wl;
#pragma unroll
    for (int k = 0; k < 8; ++k)
        out[ob + (size_t)k * NS * NS] = res[k];
}

extern "C" void kernel_launch(void* const* d_in, const int* in_sizes, int n_in,
                              void* d_out, int out_size, void* d_ws, size_t ws_size,
                              hipStream_t stream) {
    const float* img = (const float*)d_in[0];   // [8,128,128,128,1] fp32
    const float* u   = (const float*)d_in[1];   // [8,8,3] fp32
    float* out = (float*)d_out;

    int blocks = NB * 16 * 16 * 4;              // 8192 (b=xcd x 16d x 16h x 4w)
    warp_resample_kernel<<<blocks, 256, 0, stream>>>(img, u, out);
}

// Round 10
// 124.510 us; speedup vs baseline: 1.2248x; 1.2248x over previous
//
#include <hip/hip_runtime.h>

// input_tensor: [8,128,128,128,1] fp32 ; random_u: [8,8,3] fp32 ; SCALE=0.2
#define NB   8
#define NS   128
#define VOX  (NS*NS*NS)

// R10 = R9 resubmitted (R9 died at container acquisition both attempts — same
// signature as R6, which passed verbatim as R7. Kernel re-audited: constant
// loop bounds, LDS < 64KB, slab indexing proven in-window, no workspace use.
// Only change: removed a dead "*0.f" term left in the mn2 line.)
//
// R9: AMORTIZE THE PER-THREAD PROLOGUE. Evidence: VALU-busy ~= 22-24 us is
// the dominant pipe (R0/R7); static inner-loop count explains only half —
// the rest is per-thread overhead (transform ~100, bounds ~60, staging
// addressing ~80, loop/store setup). R5 (4 voxels/thread) doubled that
// overhead per voxel and regressed; R9/R10 goes the other way: 16 vox/thread.
// Tile 32w x 8h x 16d, 256 threads, 4096 blocks. Slab: kd<=15 -> p0 span <=
// 15 + 7*0.1 + 31*0.1 = 18.8 -> SD = 21 rows; SH = 13; ROW_W = 40.
// SLAB = 21*520*4 = 43,680 B -> 3 blocks/CU = 12 waves/CU — equal to the
// measured average residency across R0-R7 (~11.4 waves/CU), so the lower
// cap should not bind while total VALU work drops ~33%.
// Keeps (verified): global_load_lds staging + LDS taps (R8 proved LDS is
// bandwidth amplification, not overhead), zero-boundary unification (R1),
// XCD pinning (R3/R7: FETCH 70->27 MB), Walsh transform, local-window
// coords, float address math (R7, exact: max index 10,919 < 2^24).
#define SD    21
#define SH    13
#define ROW_W 40
#define RST   (SH*ROW_W)     // 520
#define SLAB  (SD*RST)       // 10,920 floats = 43,680 B

typedef __attribute__((address_space(1))) const void gconst_t;
typedef __attribute__((address_space(3))) void lds_t;

__global__ __launch_bounds__(256) void warp_resample_kernel(
        const float* __restrict__ img, const float* __restrict__ u,
        float* __restrict__ out) {
    __shared__ __align__(16) float slab[SLAB];

    const int tid = threadIdx.x;
    // XCD pinning: b = bi&7 -> one batch per XCD-private L2
    const int bi   = blockIdx.x;
    const int b    =  bi & 7;
    const int idx  =  bi >> 3;
    const int wblk =  idx & 3;          // 4 w-tiles of 32
    const int hblk = (idx >> 2) & 15;   // 16 h-tiles of 8
    const int dblk =  idx >> 6;         // 8 d-tiles of 16

    // ---- transform: all lanes uniform (Walsh butterfly; 1/8 folded in) ----
    const float* ub = u + b * 24;
    float T[3][4];
#pragma unroll
    for (int i = 0; i < 3; ++i) {
        float v[8];
#pragma unroll
        for (int n = 0; n < 8; ++n) {
            const float sg = (n & (4 >> i)) ? 1.f : -1.f;
            v[n] = fmaf(sg * 0.025f, ub[n * 3 + i], sg * 0.1f);  // sg*(0.8+0.2u)/8
        }
        const float a0 = v[0] + v[1], a1 = v[2] + v[3];
        const float a2 = v[4] + v[5], a3 = v[6] + v[7];
        const float d0 = v[1] - v[0], d1 = v[3] - v[2];
        const float d2 = v[5] - v[4], d3 = v[7] - v[6];
        const float A01 = a0 + a1, A23 = a2 + a3;
        T[i][0] = A23 - A01;
        T[i][1] = (a1 - a0) + (a3 - a2);
        T[i][2] = (d0 + d1) + (d2 + d3);
        T[i][3] = A01 + A23;
    }
    const float t00 = T[0][0], t01 = T[0][1], t02 = T[0][2], t03 = T[0][3];
    const float t10 = T[1][0], t11 = T[1][1], t12 = T[1][2], t13 = T[1][3];
    const float t20 = T[2][0], t21 = T[2][1], t22 = T[2][2], t23 = T[2][3];

    const int d0i = dblk << 4, h0i = hblk << 3, w0i = wblk << 5;
    const float inv = 2.0f / 127.0f;
    const float x0 = -1.f + d0i * inv, y0 = -1.f + h0i * inv, z0 = -1.f + w0i * inv;
    // pixel coords at tile origin; per-index pixel delta == t (inv*63.5 == 1)
    const float P0 = (t00 * x0 + t01 * y0 + t02 * z0 + t03 + 1.f) * 63.5f;
    const float P1 = (t10 * x0 + t11 * y0 + t12 * z0 + t13 + 1.f) * 63.5f;
    const float P2 = (t20 * x0 + t21 * y0 + t22 * z0 + t23 + 1.f) * 63.5f;

    // tile bounds via corner extremes (kd<=15, kh<=7, kw<=31)
    const float mn0 = P0 + fminf(0.f,15.f*t00)+fminf(0.f,7.f*t01)+fminf(0.f,31.f*t02);
    const float mx0 = P0 + fmaxf(0.f,15.f*t00)+fmaxf(0.f,7.f*t01)+fmaxf(0.f,31.f*t02);
    const float mn1 = P1 + fminf(0.f,15.f*t10)+fminf(0.f,7.f*t11)+fminf(0.f,31.f*t12);
    const float mx1 = P1 + fmaxf(0.f,15.f*t10)+fmaxf(0.f,7.f*t11)+fmaxf(0.f,31.f*t12);
    const float mn2 = P2 + fminf(0.f,15.f*t20)+fminf(0.f,7.f*t21)+fminf(0.f,31.f*t22);
    const float mx2 = P2 + fmaxf(0.f,15.f*t20)+fmaxf(0.f,7.f*t21)+fmaxf(0.f,31.f*t22);

    const int i0mn = (int)floorf(mn0), i0mx = (int)floorf(mx0);
    const int i1mn = (int)floorf(mn1), i1mx = (int)floorf(mx1);
    const int i2mn = (int)floorf(mn2), i2mx = (int)floorf(mx2);

    // UNCLAMPED window origin (may be negative / past the image)
    const int d_lo = i0mn;
    const int h_lo = i1mn;
    const int ws   = (i2mn - 1) & ~3;          // 4-aligned floor (works for <0)
    const int Sd   = min(i0mx + 2 - d_lo, SD); // staged d-planes <= 21
    const int Sh   = min(i1mx + 2 - h_lo, SH); // staged h-rows   <= 13

    // block-uniform: is the whole staged window inside the image?
    const int allin = __builtin_amdgcn_readfirstlane(
        (d_lo >= 0 && d_lo + Sd <= NS &&
         h_lo >= 0 && h_lo + Sh <= NS &&
         ws   >= 0 && ws + ROW_W <= NS) ? 1 : 0);

    // local-window coordinates (fold window origin into the uniform part)
    const float Pl0 = P0 - (float)d_lo;
    const float Pl1 = P1 - (float)h_lo;
    const float Pl2 = P2 - (float)ws;

    // ---- boundary blocks only: zero-fill slab so OOB taps read 0.0 ----
    if (!allin) {
        float4* p = (float4*)slab;
        for (int i = tid; i < SLAB / 4; i += 256)   // 2730 float4s
            p[i] = make_float4(0.f, 0.f, 0.f, 0.f);
        __syncthreads();   // zeros visible before any LDS-DMA write can land
    }

    // ---- stage slab: Sd*Sh rows of ROW_W floats via global_load_lds x16 ----
    // lane-task: hi = tid/10, chunk = tid%10; LDS float offset = 4*tid exactly,
    // so per-wave LDS base = di*RST + 256*wave (wave-uniform base + lane*16B).
    {
        const float* gb = img + (size_t)b * VOX;
        const int hi = tid / 10;
        const int c  = tid - hi * 10;
        const int wvbase = (tid & ~63) << 2;                  // floats
        if (allin) {
            if (hi < Sh) {
                for (int di = 0; di < Sd; ++di) {
                    const float* g = gb + (((d_lo + di) * NS + (h_lo + hi)) * NS
                                           + ws + (c << 2));
                    __builtin_amdgcn_global_load_lds(
                        (gconst_t*)g, (lds_t*)(slab + di * RST + wvbase), 16, 0, 0);
                }
            }
        } else {
            // fully-valid 16B chunks only; skipped chunks keep their zeros
            const int  cc = ws + (c << 2);
            const bool ok = (hi < Sh) && ((unsigned)(h_lo + hi) < NS)
                                      && ((unsigned)cc <= NS - 4);
            if (ok) {
                for (int di = 0; di < Sd; ++di) {
                    if ((unsigned)(d_lo + di) < NS) {
                        const float* g = gb + (((d_lo + di) * NS + (h_lo + hi)) * NS
                                               + cc);
                        __builtin_amdgcn_global_load_lds(
                            (gconst_t*)g, (lds_t*)(slab + di * RST + wvbase), 16, 0, 0);
                    }
                }
            }
        }
    }
    __syncthreads();

    // ---- unified compute: lanes dense along w; 16 voxels along d/thread ----
    // ql >= 0 always (origin = floor of tile min); every tap's LOCAL index is
    // in-window by the span analysis; OOB-image slots read staged 0.
    const int wl = tid & 31, hh = tid >> 5;
    float ql0 = Pl0 + hh * t01 + wl * t02;
    float ql1 = Pl1 + hh * t11 + wl * t12;
    float ql2 = Pl2 + hh * t21 + wl * t22;

    float res[16];
#pragma unroll
    for (int k = 0; k < 16; ++k) {
        const float f0 = floorf(ql0), f1 = floorf(ql1), f2 = floorf(ql2);
        const float r0 = ql0 - f0,    r1 = ql1 - f1,    r2 = ql2 - f2;

        // float address build: exact integer arithmetic in fp32 (<= 10,919)
        const int base = (int)fmaf(f0, (float)RST, fmaf(f1, (float)ROW_W, f2));
        const int base2 = base + RST;

        const float a00 = slab[base],           b00 = slab[base + 1];
        const float a01 = slab[base + ROW_W],   b01 = slab[base + ROW_W + 1];
        const float a10 = slab[base2],          b10 = slab[base2 + 1];
        const float a11 = slab[base2 + ROW_W],  b11 = slab[base2 + ROW_W + 1];

        const float e0 = fmaf(r2, b00 - a00, a00);
        const float e1 = fmaf(r2, b01 - a01, a01);
        const float e2 = fmaf(r2, b10 - a10, a10);
        const float e3 = fmaf(r2, b11 - a11, a11);
        const float c0 = fmaf(r1, e1 - e0, e0);
        const float c1 = fmaf(r1, e3 - e2, e2);
        res[k] = fmaf(r0, c1 - c0, c0);

        ql0 += t00; ql1 += t10; ql2 += t20;
    }

    // stores: wave = 2 h-rows x 32 consecutive w -> coalesced 128B segments
    size_t ob = (((size_t)(b * NS + d0i) * NS + (h0i + hh)) * NS) + w0i + wl;
#pragma unroll
    for (int k = 0; k < 16; ++k)
        out[ob + (size_t)k * NS * NS] = res[k];
}

extern "C" void kernel_launch(void* const* d_in, const int* in_sizes, int n_in,
                              void* d_out, int out_size, void* d_ws, size_t ws_size,
                              hipStream_t stream) {
    const float* img = (const float*)d_in[0];   // [8,128,128,128,1] fp32
    const float* u   = (const float*)d_in[1];   // [8,8,3] fp32
    float* out = (float*)d_out;

    int blocks = NB * 8 * 16 * 4;               // 4096 (b=xcd x 8d x 16h x 4w)
    warp_resample_kernel<<<blocks, 256, 0, stream>>>(img, u, out);
}